// Round 6
// baseline (1736.888 us; speedup 1.0000x reference)
//
#include <hip/hip_runtime.h>

// B=64, S=512, I=256, O=256 fp32 LSTM.
// out = [h_seq (64*512*256)] [hT (64*256)] [cT (64*256)]
//
// Phase A: xg = x @ Wx^T + bx + bh  (fp32 LDS-tiled GEMM, unchanged)
// Phase B: one block per batch (64 blocks, 512 threads, 1 block/CU).
//   Thread t: row-group rg=t>>3 (elements 4rg..4rg+3, all 4 gates = 16 rows),
//   k-slice q=t&7 (k in [32q,32q+32)). 512 products/thread = 256 v_pk_fma_f16.
//   Weights: 12 rows (gates f,i,g) persistent in VGPRs (192 regs); 4 rows
//   (gate o) streamed from LDS (128 KB, conflict-free linear layout).
//   h slice: 4 ds_read_b128 per step (80B-padded slices -> disjoint banks).
//   k-reduction: in-wave DPP butterfly (quad_perm xor1/xor2; xor4 via
//   row_ror + complementary bank_masks). NO readlanes, NO LDS broadcast
//   reads, NO io exchange arrays; ONE barrier per step.
// R5 fix: xor4add had the ror directions swapped. row_ror:n gives lane i the
//   value of lane (i-n) mod 16 (data moves toward HIGHER lanes). So lanes
//   0-3/8-11 (want l+4) need ror:12, lanes 4-7/12-15 (want l-4) need ror:4.

#define SS 512

typedef _Float16 h2 __attribute__((ext_vector_type(2)));

__device__ __forceinline__ h2 bch(unsigned u) { return __builtin_bit_cast(h2, u); }

#if __has_builtin(__builtin_amdgcn_fdot2)
__device__ __forceinline__ float dot2f(h2 a, h2 b, float c) {
  return __builtin_amdgcn_fdot2(a, b, c, false);
}
#else
__device__ __forceinline__ float dot2f(h2 a, h2 b, float c) {
  return c + (float)a[0] * (float)b[0] + (float)a[1] * (float)b[1];
}
#endif

__device__ __forceinline__ h2 pkfma(h2 a, h2 b, h2 c) {
  return __builtin_elementwise_fma(a, b, c);
}

// y += value from lane^CTRL partner (quad_perm DPP), CTRL compile-time
template <int CTRL>
__device__ __forceinline__ float dppadd(float x) {
  int s = __builtin_bit_cast(int, x);
  int v = __builtin_amdgcn_update_dpp(0, s, CTRL, 0xF, 0xF, true);
  return x + __builtin_bit_cast(float, v);
}

// y += value from lane^4 partner within each 8-lane group.
// row_ror:n -> dst lane i = src lane (i-n) mod 16.
// lanes 0-3, 8-11 (banks 0,2; bank_mask 0x5): want src l+4 -> ror:12
// lanes 4-7,12-15 (banks 1,3; bank_mask 0xA): want src l-4 -> ror:4
__device__ __forceinline__ float xor4add(float x) {
  int s = __builtin_bit_cast(int, x);
  int v = __builtin_amdgcn_update_dpp(0, s, 0x12C, 0xF, 0x5, false);  // ror:12
  v = __builtin_amdgcn_update_dpp(v, s, 0x124, 0xF, 0xA, false);      // ror:4
  return x + __builtin_bit_cast(float, v);
}

__device__ __forceinline__ float sigm(float x) { return 1.f / (1.f + __expf(-x)); }
__device__ __forceinline__ float tanh_f(float x) {
  float e = __expf(-2.f * fabsf(x));      // e in (0,1], no overflow
  float r = (1.f - e) / (1.f + e);
  return copysignf(r, x);
}

// ---------------------------------------------------------------- Phase A
__global__ __launch_bounds__(256) void xg_gemm(
    const float* __restrict__ X, const float* __restrict__ W,
    const float* __restrict__ bx, const float* __restrict__ bh,
    float* __restrict__ out)
{
  __shared__ float As[64][68];
  __shared__ float Bs[64][68];
  const int bm = blockIdx.x >> 4;
  const int bn = blockIdx.x & 15;
  const int tid = threadIdx.x;
  const int tn = tid & 15, tm = tid >> 4;
  const int row0 = bm * 64, col0 = bn * 64;
  float acc[4][4] = {};

  for (int k0 = 0; k0 < 256; k0 += 64) {
#pragma unroll
    for (int i = 0; i < 4; i++) {
      const int m = (tid >> 4) + i * 16;
      const int k = (tid & 15) * 4;
      float4 av = *(const float4*)&X[(size_t)(row0 + m) * 256 + k0 + k];
      *(float4*)&As[m][k] = av;
      float4 wv = *(const float4*)&W[(size_t)(col0 + m) * 256 + k0 + k];
      Bs[k + 0][m] = wv.x; Bs[k + 1][m] = wv.y;
      Bs[k + 2][m] = wv.z; Bs[k + 3][m] = wv.w;
    }
    __syncthreads();
#pragma unroll 8
    for (int kk = 0; kk < 64; kk++) {
      const float a0 = As[tm * 4 + 0][kk];
      const float a1 = As[tm * 4 + 1][kk];
      const float a2 = As[tm * 4 + 2][kk];
      const float a3 = As[tm * 4 + 3][kk];
      const float4 bv = *(const float4*)&Bs[kk][tn * 4];
      acc[0][0] = fmaf(a0, bv.x, acc[0][0]); acc[0][1] = fmaf(a0, bv.y, acc[0][1]);
      acc[0][2] = fmaf(a0, bv.z, acc[0][2]); acc[0][3] = fmaf(a0, bv.w, acc[0][3]);
      acc[1][0] = fmaf(a1, bv.x, acc[1][0]); acc[1][1] = fmaf(a1, bv.y, acc[1][1]);
      acc[1][2] = fmaf(a1, bv.z, acc[1][2]); acc[1][3] = fmaf(a1, bv.w, acc[1][3]);
      acc[2][0] = fmaf(a2, bv.x, acc[2][0]); acc[2][1] = fmaf(a2, bv.y, acc[2][1]);
      acc[2][2] = fmaf(a2, bv.z, acc[2][2]); acc[2][3] = fmaf(a2, bv.w, acc[2][3]);
      acc[3][0] = fmaf(a3, bv.x, acc[3][0]); acc[3][1] = fmaf(a3, bv.y, acc[3][1]);
      acc[3][2] = fmaf(a3, bv.z, acc[3][2]); acc[3][3] = fmaf(a3, bv.w, acc[3][3]);
    }
    __syncthreads();
  }

  float bias[4];
#pragma unroll
  for (int j = 0; j < 4; j++) {
    const int col = col0 + tn * 4 + j;
    bias[j] = bx[col] + bh[col];
  }
#pragma unroll
  for (int i = 0; i < 4; i++) {
    float4 o4;
    o4.x = acc[i][0] + bias[0]; o4.y = acc[i][1] + bias[1];
    o4.z = acc[i][2] + bias[2]; o4.w = acc[i][3] + bias[3];
    *(float4*)&out[(size_t)(row0 + tm * 4 + i) * 1024 + col0 + tn * 4] = o4;
  }
}

// ---------------------------------------------------------------- Phase B
// Row slot r in [0,16): gate gt=r>>2, element er=r&3, global row
// R = gt*256 + 4*rg + er. Slots 0..11 (f,i,g) in VGPRs; slots 12..15 (o)
// streamed from LDS. h slice layout: 8 slices of 40 halves (32 data + 8 pad,
// 80B stride -> slice s starts at bank 20s%32, all 8 disjoint bank-quads).
__global__ __launch_bounds__(512, 2) void lstm_scan6(
    const float* __restrict__ xg,   // [64][512][1024]
    const float* __restrict__ Wh,   // [1024][256]
    const float* __restrict__ h0,   // [64][256]
    const float* __restrict__ c0,   // [64][256]
    float* __restrict__ out)
{
  // wl: [row'(4)][j4(4)][tid(512)][8 halves] -> per-lane contiguous 16B
  __shared__ __align__(16) _Float16 wl[4 * 4 * 512 * 8];   // 128 KB
  __shared__ __align__(16) _Float16 h_sh[2][8 * 40];       // 2 x 640 B

  const int t = threadIdx.x;
  const int b = blockIdx.x;
  const int rg = t >> 3;          // row group: elements 4rg..4rg+3
  const int q  = t & 7;           // k-slice
  const int e  = q & 3;           // owned element within group (if owner)
  const bool owner = (q < 4);
  const int m  = 4 * rg + e;      // owned element index [0,256)
  const int kb = 32 * q;          // k base

  // ---- persistent register weights: slots 0..11 (gates f,i,g)
  h2 wv[12][16];
#pragma unroll
  for (int r = 0; r < 12; ++r) {
    const float* row = Wh + (size_t)((r >> 2) * 256 + 4 * rg + (r & 3)) * 256 + kb;
#pragma unroll
    for (int j = 0; j < 16; ++j) {
      float2 a = *(const float2*)&row[2 * j];
      h2 x; x[0] = (_Float16)a.x; x[1] = (_Float16)a.y;
      wv[r][j] = x;
    }
  }
  // ---- LDS weights: slots 12..15 (gate o)
#pragma unroll
  for (int rp = 0; rp < 4; ++rp) {
    const float* row = Wh + (size_t)(768 + 4 * rg + rp) * 256 + kb;
#pragma unroll
    for (int j4 = 0; j4 < 4; ++j4) {
      const int hb = ((rp * 4 + j4) * 512 + t) * 8;
#pragma unroll
      for (int d = 0; d < 4; ++d) {
        float2 a = *(const float2*)&row[8 * j4 + 2 * d];
        wl[hb + 2 * d + 0] = (_Float16)a.x;
        wl[hb + 2 * d + 1] = (_Float16)a.y;
      }
    }
  }
  // ---- initial state
  if (t < 256) h_sh[0][(t >> 5) * 40 + (t & 31)] = (_Float16)h0[(size_t)b * 256 + t];
  float cr = owner ? c0[(size_t)b * 256 + m] : 0.f;
  __syncthreads();

  const float* xr = xg + (size_t)b * SS * 1024;
  float* hs = out + (size_t)b * SS * 256;
  h2 kOne; kOne[0] = (_Float16)1.0f; kOne[1] = (_Float16)1.0f;

  for (int s = 0; s < SS; ++s) {
    const int p = s & 1;
    // prefetch xg for owned element (hidden under the dot phase)
    float x_f = 0.f, x_i = 0.f, x_g = 0.f, x_o = 0.f;
    if (owner) {
      const float* xp = xr + (size_t)s * 1024 + m;
      x_f = xp[0]; x_i = xp[256]; x_g = xp[512]; x_o = xp[768];
    }

    h2 acc[16] = {};
#pragma unroll
    for (int i = 0; i < 4; ++i) {
      const uint4 hw = *(const uint4*)&h_sh[p][q * 40 + i * 8];  // 16B of h slice
#pragma unroll
      for (int r = 0; r < 12; ++r) {
        acc[r] = pkfma(wv[r][4 * i + 0], bch(hw.x), acc[r]);
        acc[r] = pkfma(wv[r][4 * i + 1], bch(hw.y), acc[r]);
        acc[r] = pkfma(wv[r][4 * i + 2], bch(hw.z), acc[r]);
        acc[r] = pkfma(wv[r][4 * i + 3], bch(hw.w), acc[r]);
      }
#pragma unroll
      for (int rp = 0; rp < 4; ++rp) {
        const uint4 wq = *(const uint4*)&wl[((rp * 4 + i) * 512 + t) * 8];
        acc[12 + rp] = pkfma(bch(wq.x), bch(hw.x), acc[12 + rp]);
        acc[12 + rp] = pkfma(bch(wq.y), bch(hw.y), acc[12 + rp]);
        acc[12 + rp] = pkfma(bch(wq.z), bch(hw.z), acc[12 + rp]);
        acc[12 + rp] = pkfma(bch(wq.w), bch(hw.w), acc[12 + rp]);
      }
    }

    // fp32 per-slot partials, then full 8-lane butterfly (static indexing)
    float y[16];
#pragma unroll
    for (int r = 0; r < 16; ++r) y[r] = dot2f(acc[r], kOne, 0.f);
#pragma unroll
    for (int r = 0; r < 16; ++r) y[r] = dppadd<0xB1>(y[r]);   // xor1
#pragma unroll
    for (int r = 0; r < 16; ++r) y[r] = dppadd<0x4E>(y[r]);   // xor2
#pragma unroll
    for (int r = 0; r < 16; ++r) y[r] = xor4add(y[r]);        // xor4

    // select own element's 4 gate sums (cndmask chains, static reg indices)
    float yg[4];
#pragma unroll
    for (int g4 = 0; g4 < 4; ++g4) {
      float z = y[4 * g4 + 0];
      z = (e == 1) ? y[4 * g4 + 1] : z;
      z = (e == 2) ? y[4 * g4 + 2] : z;
      z = (e == 3) ? y[4 * g4 + 3] : z;
      yg[g4] = z;
    }

    if (owner) {
      const float f  = sigm(yg[0] + x_f);
      const float ii = sigm(yg[1] + x_i);
      const float gg = tanh_f(yg[2] + x_g);
      const float oo = sigm(yg[3] + x_o);
      cr = cr * f + ii * gg;
      const float h = oo * tanh_f(cr);
      hs[(size_t)s * 256 + m] = h;
      h_sh[p ^ 1][(m >> 5) * 40 + (m & 31)] = (_Float16)h;
      if (s == SS - 1) {
        out[8388608 + (size_t)b * 256 + m] = h;    // hT
        out[8404992 + (size_t)b * 256 + m] = cr;   // cT
      }
    }
    __syncthreads();   // h_sh[p^1] complete; also fences reuse of h_sh[p]
  }
}

// ---------------------------------------------------------------- launch
extern "C" void kernel_launch(void* const* d_in, const int* in_sizes, int n_in,
                              void* d_out, int out_size, void* d_ws, size_t ws_size,
                              hipStream_t stream) {
  const float* x  = (const float*)d_in[0];
  const float* h0 = (const float*)d_in[1];
  const float* c0 = (const float*)d_in[2];
  const float* Wh = (const float*)d_in[3];
  const float* bh = (const float*)d_in[4];
  const float* Wx = (const float*)d_in[5];
  const float* bx = (const float*)d_in[6];
  float* out = (float*)d_out;

  float* xg = (float*)d_ws;   // 32768*1024 floats = 128 MB

  xg_gemm<<<dim3(8192), dim3(256), 0, stream>>>(x, Wx, bx, bh, xg);
  lstm_scan6<<<dim3(64), dim3(512), 0, stream>>>(xg, Wh, h0, c0, out);
}